// Round 19
// baseline (322.990 us; speedup 1.0000x reference)
//
#include <hip/hip_runtime.h>

// SNN forward: [merged preps: X->bits, W1/W2 hi/lo] ->
// [GEMM1+scan1: W1-slice RESIDENT in LDS, A decoded from X bits in regs,
//  ZERO K-loop barriers/DMA-drains] -> GEMM2 (bit-decoded A, R17) -> scan2.
// f16 split-2: W = hi + lo, residual ~2^-24 => fp32-grade MFMA results.
// X and spikes are binary -> carried as bits (1 MB / 4 MB).
// Lessons: barrier vmcnt(0) drains all outstanding DMA (m97/m99) -> only fix
// is removing DMA from the K-loop (this round); compile-time ring indices
// (R9); register-dbuf VGPR cliff (R11/R12); phase fusion into g1s1 loses (R14).

#define NN 64
#define II 256
#define HH 1024
#define OO 18
#define TT 500

#define D_SR 0.9048374180359595f   // exp(-1/10)
#define C_SR 0.27182818284590454f  // e/10
#define D_RF 0.36787944117144233f  // exp(-1)
#define C_RF 2.718281828459045f    // e
#define THETA 10.0f
#define REFS (-20.0f)

typedef _Float16 f16;
typedef _Float16 f16x8 __attribute__((ext_vector_type(8)));
typedef float f32x4 __attribute__((ext_vector_type(4)));
typedef unsigned long long u64;
typedef unsigned int u32;

__device__ __forceinline__ void gl2lds16(const void* g, void* l) {
    __builtin_amdgcn_global_load_lds(
        (const __attribute__((address_space(1))) void*)g,
        (__attribute__((address_space(3))) void*)l, 16, 0, 0);
}

// ---------------- merged prep: X -> bits, W1 hi/lo, W2 hi/lo ----------------
// grid 3200: [0,2048) X bit-pack tiles, [2048,3072) W1, [3072,3200) W2.
__launch_bounds__(256)
__global__ void prep_all(const float* __restrict__ X, const float* __restrict__ W1,
                         const float* __restrict__ W2, u64* __restrict__ Xbits,
                         f16* __restrict__ W1h, f16* __restrict__ W1l,
                         f16* __restrict__ W2h, f16* __restrict__ W2l) {
    __shared__ float tile[64][65];
    const int b = blockIdx.x;
    const int tid = threadIdx.x;

    if (b < 2048) {
        // X [N][I][T] f32 (binary) -> Xbits [n*TT+t][4] u64 (bit i = X[n][i][t])
        const int t0 = (b & 7) * 64, i0 = ((b >> 3) & 3) * 64, n = b >> 5;
        const int tx = tid & 63, q = tid >> 6;
        const float* Xn = X + (size_t)n * II * TT;
#pragma unroll 4
        for (int j = 0; j < 16; ++j) {
            int il = j * 4 + q;
            int t = t0 + tx;
            tile[il][tx] = (t < TT) ? Xn[(size_t)(i0 + il) * TT + t] : 0.f;
        }
        __syncthreads();
        const int wv = tid >> 6, ln = tid & 63;
#pragma unroll 4
        for (int tt = 0; tt < 16; ++tt) {
            int tl = wv * 16 + tt;
            float v = tile[ln][tl];
            u64 bm = __ballot(v != 0.0f);
            int t = t0 + tl;
            if (ln == 0 && t < TT)
                Xbits[((size_t)n * TT + t) * 4 + (i0 >> 6)] = bm;
        }
    } else if (b < 3072) {
        int idx = (b - 2048) * 256 + tid;
        float w = W1[idx];
        f16 h = (f16)w;
        f16 l = (f16)(w - (float)h);
        W1h[idx] = h;
        W1l[idx] = l;
    } else {
        int idx = (b - 3072) * 256 + tid;
        int o = idx >> 10;
        float w = (o < OO) ? W2[idx] : 0.f;
        f16 h = (f16)w;
        f16 l = (f16)(w - (float)h);
        W2h[idx] = h;
        W2l[idx] = l;
    }
}

// ---------------- FUSED layer 1: resident-B, bit-A, barrier-free K-loop -----
// grid (16, 64) = 1024 blocks, 512 thr (8 waves). Block = (n, 64-h tile).
// LDS: Bh/Bl 64x264 f16 (67.6 KB, resident all kernel) + yb 128x68 f32
// (34.8 KB) + Xbits 128x9 u32 (4.6 KB) = 107 KB -> 1 block/CU.
// Per chunk (128 t): stage 4 KB bits, BAR, K-loop (8 iters: ds_read B +
// reg-decode A + 8 MFMA, NO barriers), epilogue->yb, BAR, scan (wave 0,
// ballot -> one u64 per t), BAR.
__launch_bounds__(512)
__global__ void gemm1_scan1(const u32* __restrict__ Xbits, const f16* __restrict__ Wh,
                            const f16* __restrict__ Wl, u64* __restrict__ Sb) {
    __shared__ __align__(16) char smem[107008];
    f16* Bh = (f16*)smem;                       // 64 x 264
    f16* Bl = Bh + 64 * 264;                    // 64 x 264
    float* yb = (float*)(smem + 67584);         // 128 x 68
    u32* bb = (u32*)(smem + 102400);            // 128 x 9

    const int tid = threadIdx.x;
    const int wave = tid >> 6, lane = tid & 63;

    // XCD swizzle: the 16 h-tiles of one n share an XCD
    const int f = blockIdx.y * 16 + blockIdx.x;
    const int x = f & 7, g = f >> 3;
    const int n = x * 8 + (g & 7);
    const int ht = g >> 3;                      // 0..15
    const int h0g = ht * 64;

    const int wm = wave & 1, wn = wave >> 1;    // 2 t-halves x 4 h-quarters
    const int fr = lane & 15, kq = lane >> 4;

    // load W1 slice resident (hi+lo), padded rows of 264 f16
    for (int e = tid; e < 4096; e += 512) {
        int mat = e >> 11, rr = (e >> 5) & 63, seg = e & 31;
        const f16* src = (mat ? Wl : Wh) + ((size_t)(h0g + rr) << 8) + seg * 8;
        f16* dst = (mat ? Bl : Bh) + rr * 264 + seg * 8;
        *(f16x8*)dst = *(const f16x8*)src;
    }

    float p1 = 0.f, a1 = 0.f, p2 = 0.f, a2 = 0.f;  // scan state (tid<64)

    for (int c = 0; c < 4; ++c) {
        const int t0 = c * 128;
        const int TCe = (TT - t0 < 128) ? (TT - t0) : 128;

        // stage X bits for this chunk: 128 rows x 8 u32 (pad to 9)
        for (int e = tid; e < 1024; e += 512) {
            int r = e >> 3, w = e & 7;
            bb[r * 9 + w] = Xbits[((size_t)(n * TT + t0) + r) * 8 + w];
        }
        __syncthreads();  // B resident + bits ready; prev scan done reading yb

        f32x4 acc[4] = {};
#pragma unroll
        for (int kk = 0; kk < 8; ++kk) {
            f16x8 bhv = *(const f16x8*)(Bh + (wn * 16 + fr) * 264 + kk * 32 + kq * 8);
            f16x8 blv = *(const f16x8*)(Bl + (wn * 16 + fr) * 264 + kk * 32 + kq * 8);
#pragma unroll
            for (int i = 0; i < 4; ++i) {
                u32 bw = bb[(wm * 64 + i * 16 + fr) * 9 + kk];
                f16x8 a;
#pragma unroll
                for (int j = 0; j < 8; ++j)
                    a[j] = ((bw >> (kq * 8 + j)) & 1u) ? (f16)1.0f : (f16)0.0f;
                acc[i] = __builtin_amdgcn_mfma_f32_16x16x32_f16(a, bhv, acc[i], 0, 0, 0);
                acc[i] = __builtin_amdgcn_mfma_f32_16x16x32_f16(a, blv, acc[i], 0, 0, 0);
            }
        }

        // epilogue: acc -> yb (t-major, stride 68)
#pragma unroll
        for (int i = 0; i < 4; ++i) {
            int tr = wm * 64 + i * 16 + kq * 4;
            int hc = wn * 16 + fr;
#pragma unroll
            for (int r = 0; r < 4; ++r)
                yb[(tr + r) * 68 + hc] = acc[i][r];
        }
        __syncthreads();

        // sequential scan (wave 0, 64 channels); ballot -> one u64 per t
        if (tid < 64) {
            u64* sq = Sb + ((size_t)(n * TT + t0)) * 16 + ht;
            float rb_[8];
#pragma unroll
            for (int j = 0; j < 8; ++j) rb_[j] = yb[j * 68 + tid];
            int t = 0;
            for (; t + 8 <= TCe; t += 8) {
#pragma unroll
                for (int j = 0; j < 8; ++j) {
                    float xv = rb_[j];
                    int tn = t + j + 8;
                    rb_[j] = (tn < TCe) ? yb[tn * 68 + tid] : 0.f;
                    a1 = D_SR * (a1 + p1);
                    p1 = D_SR * p1 + xv;
                    float ut = C_SR * a1;
                    a2 = D_RF * (a2 + p2);
                    float u = ut + C_RF * a2;
                    float s = (u >= THETA) ? 1.0f : 0.0f;
                    p2 = D_RF * p2 + REFS * s;
                    u64 bm = __ballot(u >= THETA);
                    if (lane == 0) sq[(size_t)(t + j) * 16] = bm;
                }
            }
            int rem = TCe - t;
#pragma unroll
            for (int j = 0; j < 8; ++j) {
                if (j < rem) {
                    float xv = rb_[j];
                    a1 = D_SR * (a1 + p1);
                    p1 = D_SR * p1 + xv;
                    float ut = C_SR * a1;
                    a2 = D_RF * (a2 + p2);
                    float u = ut + C_RF * a2;
                    float s = (u >= THETA) ? 1.0f : 0.0f;
                    p2 = D_RF * p2 + REFS * s;
                    u64 bm = __ballot(u >= THETA);
                    if (lane == 0) sq[(size_t)(t + j) * 16] = bm;
                }
            }
        }
        __syncthreads();  // yb/bits reads done; next chunk may overwrite
    }
}

// ---------------- GEMM2: bitmask-decoded A, split-f16 B, dbuf (R17) ---------
// grid 500; 256 thr; tile 64 m x 32 o; K=1024, BK=32.
__launch_bounds__(256)
__global__ void gemm2_mfma(const u64* __restrict__ Sb, const f16* __restrict__ W2h,
                           const f16* __restrict__ W2l, float* __restrict__ Y2) {
    __shared__ u32 bits[64 * 33];                 // 8,448 B
    __shared__ __align__(16) f16 Bh[2][32 * 32];  // 2 x 2 KB
    __shared__ __align__(16) f16 Bl[2][32 * 32];  // 2 x 2 KB

    const int tid = threadIdx.x;
    const int wave = tid >> 6, lane = tid & 63;
    const int m0 = blockIdx.x * 64;
    const int fr = lane & 15, kq = lane >> 4;

    const u32* g32 = (const u32*)Sb + (size_t)m0 * 32;
    for (int e = tid; e < 2048; e += 256)
        bits[(e >> 5) * 33 + (e & 31)] = g32[e];

    const f16* gB = (wave < 2 ? W2h : W2l) + (size_t)((wave & 1) * 16 + (lane >> 2)) * HH + (lane & 3) * 8;

    auto stageB = [&](int kk2, int b) {
        gl2lds16(gB + kk2 * 32, (wave < 2 ? &Bh[b][0] : &Bl[b][0]) + (wave & 1) * 512);
    };

    stageB(0, 0);

    f32x4 acc[2] = {};
    const int brow = (wave * 16 + fr) * 33;
    const f16 onef = (f16)1.0f, zerof = (f16)0.0f;
    for (int kk = 0; kk < HH / 32; ++kk) {
        __syncthreads();
        if (kk < HH / 32 - 1) stageB(kk + 1, (kk + 1) & 1);
        const int b = kk & 1;

        u32 bw = bits[brow + kk];
        f16x8 a;
#pragma unroll
        for (int j = 0; j < 8; ++j)
            a[j] = ((bw >> (kq * 8 + j)) & 1u) ? onef : zerof;

        f16x8 bh[2], bl[2];
#pragma unroll
        for (int j = 0; j < 2; ++j) {
            bh[j] = *(const f16x8*)(&Bh[b][(j * 16 + fr) * 32 + kq * 8]);
            bl[j] = *(const f16x8*)(&Bl[b][(j * 16 + fr) * 32 + kq * 8]);
        }
#pragma unroll
        for (int j = 0; j < 2; ++j) {
            acc[j] = __builtin_amdgcn_mfma_f32_16x16x32_f16(a, bh[j], acc[j], 0, 0, 0);
            acc[j] = __builtin_amdgcn_mfma_f32_16x16x32_f16(a, bl[j], acc[j], 0, 0, 0);
        }
    }

#pragma unroll
    for (int j = 0; j < 2; ++j) {
        int rbase = m0 + wave * 16 + kq * 4;
        int cc = j * 16 + fr;
        float* p = Y2 + (size_t)rbase * 32 + cc;
#pragma unroll
        for (int r = 0; r < 4; ++r)
            p[(size_t)r * 32] = acc[j][r];
    }
}

// ---------------- scan2: single-phase LDS, static-index ring ----------------
__launch_bounds__(256)
__global__ void scan2_k(const float* __restrict__ Y2, float* __restrict__ Out) {
    __shared__ float yc[TT * 32];    // 64,000 B
    __shared__ float sb[OO * TT];    // 36,000 B
    const int n = blockIdx.x, tid = threadIdx.x;

    const float4* src = (const float4*)(Y2 + (size_t)n * TT * 32);
    float4* dst = (float4*)yc;
    for (int i = tid; i < TT * 8; i += 256) dst[i] = src[i];
    __syncthreads();

    if (tid < 32) {
        float p1 = 0.f, a1 = 0.f, p2 = 0.f, a2 = 0.f;
        float rb_[8];
#pragma unroll
        for (int j = 0; j < 8; ++j) rb_[j] = yc[j * 32 + tid];
        int t = 0;
        for (; t + 8 <= TT; t += 8) {
#pragma unroll
            for (int j = 0; j < 8; ++j) {
                float xv = rb_[j];
                int tn = t + j + 8;
                rb_[j] = (tn < TT) ? yc[tn * 32 + tid] : 0.f;
                a1 = D_SR * (a1 + p1);
                p1 = D_SR * p1 + xv;
                float ut = C_SR * a1;
                a2 = D_RF * (a2 + p2);
                float u = ut + C_RF * a2;
                float s = (u >= THETA) ? 1.0f : 0.0f;
                p2 = D_RF * p2 + REFS * s;
                if (tid < OO) sb[tid * TT + t + j] = s;
            }
        }
#pragma unroll
        for (int j = 0; j < 8; ++j) {
            if (t + j < TT) {
                float xv = rb_[j];
                a1 = D_SR * (a1 + p1);
                p1 = D_SR * p1 + xv;
                float ut = C_SR * a1;
                a2 = D_RF * (a2 + p2);
                float u = ut + C_RF * a2;
                float s = (u >= THETA) ? 1.0f : 0.0f;
                p2 = D_RF * p2 + REFS * s;
                if (tid < OO) sb[tid * TT + t + j] = s;
            }
        }
    }
    __syncthreads();

    float* on = Out + (size_t)n * OO * TT;
    for (int e = tid; e < OO * TT; e += 256) on[e] = sb[e];
}

extern "C" void kernel_launch(void* const* d_in, const int* in_sizes, int n_in,
                              void* d_out, int out_size, void* d_ws, size_t ws_size,
                              hipStream_t stream) {
    const float* X  = (const float*)d_in[0];
    const float* W1 = (const float*)d_in[1];
    const float* W2 = (const float*)d_in[2];
    float* out = (float*)d_out;

    const size_t s_sb = (size_t)NN * TT * 16 * 8;        //  4,096,000 (spike bits)
    const size_t s_xb = (size_t)(NN * TT + 128) * 32;    //  1,028,096 (X bits + slack)
    const size_t s_xb_pad = 1048576;
    const size_t s_W  = (size_t)HH * II * 2;             //    524,288 (x2)
    const size_t s_W2 = (size_t)32 * HH * 2;             //     65,536 (x2)
    // + y2 4,096,000 => ~10.4 MB total
    (void)s_xb;

    char* w = (char*)d_ws;
    u64*   sb   = (u64*)w;   w += s_sb;
    u64*   xbit = (u64*)w;   w += s_xb_pad;
    f16*   W1h  = (f16*)w;   w += s_W;
    f16*   W1l  = (f16*)w;   w += s_W;
    f16*   W2h  = (f16*)w;   w += s_W2;
    f16*   W2l  = (f16*)w;   w += s_W2;
    float* y2   = (float*)w;

    prep_all<<<3200, 256, 0, stream>>>(X, W1, W2, xbit, W1h, W1l, W2h, W2l);

    gemm1_scan1<<<dim3(16, 64), 512, 0, stream>>>((const u32*)xbit, W1h, W1l, sb);

    gemm2_mfma<<<(NN * TT) / 64, 256, 0, stream>>>(sb, W2h, W2l, y2);
    scan2_k<<<NN, 256, 0, stream>>>(y2, out);
}

// Round 20
// 189.942 us; speedup vs baseline: 1.7005x; 1.7005x over previous
//
#include <hip/hip_runtime.h>

// SNN forward (FINAL, empirically-best R16 config): [merged preps] ->
// [GEMM1+scan1 fused, 128x128, LDS-dbuf K-loop, 512 thr / 8 waves] ->
// GEMM2 (64-row, 500 blk) -> scan2 (single-phase LDS, static ring).
// f16 split-2: W = hi + lo (both f16), residual ~2^-24 => fp32-grade MFMA.
// Session lessons (R0-R18):
//  - ring/dbuf arrays need compile-time indices or they spill to scratch (R9/R10)
//  - LDS-staged dbuf w/ 1 barrier/iter is g1s1's optimum; register-dbuf hits
//    the VGPR cliff (R11/R12: 200 VGPR = 2x slower); fragment-order layouts
//    don't help (R12); occupancy 11/21/39/41% all give ~66us (R6/R13/R16):
//    pinned by barrier vmcnt(0) DMA drain (the m97 plateau mechanism)
//  - phase fusion into g1s1 serializes at a net loss (R14); in-K-loop bit
//    decode is VALU-bound death (R18: MfmaUtil 6.8%, 3x regress)
//  - spike bit-packing cuts 125 MB traffic but buys ~0 (R17): not BW-bound

#define NN 64
#define II 256
#define HH 1024
#define OO 18
#define TT 500

#define D_SR 0.9048374180359595f   // exp(-1/10)
#define C_SR 0.27182818284590454f  // e/10
#define D_RF 0.36787944117144233f  // exp(-1)
#define C_RF 2.718281828459045f    // e
#define THETA 10.0f
#define REFS (-20.0f)

typedef _Float16 f16;
typedef _Float16 f16x8 __attribute__((ext_vector_type(8)));
typedef float f32x4 __attribute__((ext_vector_type(4)));

__device__ __forceinline__ void gl2lds16(const void* g, void* l) {
    __builtin_amdgcn_global_load_lds(
        (const __attribute__((address_space(1))) void*)g,
        (__attribute__((address_space(3))) void*)l, 16, 0, 0);
}

// ---------------- merged prep: X transpose + W1 hi/lo + W2 hi/lo ------------
// grid 3200: [0,2048) prep_x tiles, [2048,3072) W1, [3072,3200) W2.
__launch_bounds__(256)
__global__ void prep_all(const float* __restrict__ X, const float* __restrict__ W1,
                         const float* __restrict__ W2, f16* __restrict__ Xb,
                         f16* __restrict__ W1h, f16* __restrict__ W1l,
                         f16* __restrict__ W2h, f16* __restrict__ W2l) {
    __shared__ float tile[64][65];
    const int b = blockIdx.x;
    const int tid = threadIdx.x;

    if (b < 2048) {
        const int t0 = (b & 7) * 64, i0 = ((b >> 3) & 3) * 64, n = b >> 5;
        const int tx = tid & 63, q = tid >> 6;
        const float* Xn = X + (size_t)n * II * TT;
#pragma unroll 4
        for (int j = 0; j < 16; ++j) {
            int il = j * 4 + q;
            int t = t0 + tx;
            tile[il][tx] = (t < TT) ? Xn[(size_t)(i0 + il) * TT + t] : 0.f;
        }
        __syncthreads();
#pragma unroll 4
        for (int j = 0; j < 16; ++j) {
            int tl = j * 4 + q;
            int t = t0 + tl;
            if (t < TT)
                Xb[((size_t)n * TT + t) * II + i0 + tx] = (f16)tile[tx][tl];
        }
    } else if (b < 3072) {
        int idx = (b - 2048) * 256 + tid;
        float w = W1[idx];
        f16 h = (f16)w;
        f16 l = (f16)(w - (float)h);
        W1h[idx] = h;
        W1l[idx] = l;
    } else {
        int idx = (b - 3072) * 256 + tid;
        int o = idx >> 10;
        float w = (o < OO) ? W2[idx] : 0.f;
        f16 h = (f16)w;
        f16 l = (f16)(w - (float)h);
        W2h[idx] = h;
        W2l[idx] = l;
    }
}

// ---------------- FUSED layer 1: 128x128 tile, dbuf K-loop, 8 waves ---------
// grid (8, 64), 512 thr. Per block: 4 t-chunks of 128.
// Wave layout 2m x 4n: wave w covers rows wm*64+[0,64), cols wn*32+[0,32).
// Staging: wave w stages rows [w*16, w*16+16) of A, Bh, Bl (3 x 1KB each).
__launch_bounds__(512)
__global__ void gemm1_scan1(const f16* __restrict__ Xb, const f16* __restrict__ Wh,
                            const f16* __restrict__ Wl, f16* __restrict__ S1) {
    __shared__ __align__(16) char smem[128 * 132 * 4];  // 67,584 B
    float* yb = (float*)smem;

    const int tid = threadIdx.x;
    const int wave = tid >> 6, lane = tid & 63;

    // XCD swizzle: the 8 h-tiles of one n share an XCD
    const int f = blockIdx.y * 8 + blockIdx.x;
    const int x = f & 7, g = f >> 3;
    const int n = x * 8 + (g & 7);
    const int ht = g >> 3;
    const int h0g = ht * 128;

    const int rbl = wave * 16 + (lane >> 2);   // staged row 0..127
    const int koff = (lane & 3) * 8;
    const f16* gBh0 = Wh + (size_t)(h0g + rbl) * II + koff;
    const f16* gBl0 = Wl + (size_t)(h0g + rbl) * II + koff;

    const int wm = wave & 1, wn = wave >> 1;   // 2m x 4n
    const int fr = lane & 15, kq = lane >> 4;

    float p1 = 0.f, a1 = 0.f, p2 = 0.f, a2 = 0.f;  // scan state (tid<128)

    for (int c = 0; c < 4; ++c) {
        const int t0 = c * 128;
        const int TCe = (TT - t0 < 128) ? (TT - t0) : 128;

        int r0 = rbl; if (r0 > TCe - 1) r0 = TCe - 1;
        const f16* gA0 = Xb + ((size_t)n * TT + t0 + r0) * II + koff;

        auto stage = [&](int kk2, int b) {
            f16* As_b = (f16*)(smem + b * 24576);
            f16* Bh_b = As_b + 4096;   // f16 elements: As = 128*32 = 4096
            f16* Bl_b = As_b + 8192;
            const int ko = kk2 * 32;
            gl2lds16(gA0 + ko, As_b + wave * 512);
            gl2lds16(gBh0 + ko, Bh_b + wave * 512);
            gl2lds16(gBl0 + ko, Bl_b + wave * 512);
        };

        stage(0, 0);  // previous chunk's post-scan barrier protects yb base

        f32x4 acc[4][2] = {};
        for (int kk = 0; kk < 8; ++kk) {
            __syncthreads();                 // buf[kk&1] DMA drained here
            if (kk < 7) stage(kk + 1, (kk + 1) & 1);

            const f16* As_b = (const f16*)(smem + (kk & 1) * 24576);
            const f16* Bh_b = As_b + 4096;
            const f16* Bl_b = As_b + 8192;

            f16x8 av[4], bhv[2], blv[2];
#pragma unroll
            for (int i = 0; i < 4; ++i)
                av[i] = *(const f16x8*)(As_b + (wm * 64 + i * 16 + fr) * 32 + kq * 8);
#pragma unroll
            for (int j = 0; j < 2; ++j) {
                bhv[j] = *(const f16x8*)(Bh_b + (wn * 32 + j * 16 + fr) * 32 + kq * 8);
                blv[j] = *(const f16x8*)(Bl_b + (wn * 32 + j * 16 + fr) * 32 + kq * 8);
            }
#pragma unroll
            for (int i = 0; i < 4; ++i)
#pragma unroll
                for (int j = 0; j < 2; ++j) {
                    acc[i][j] = __builtin_amdgcn_mfma_f32_16x16x32_f16(av[i], bhv[j], acc[i][j], 0, 0, 0);
                    acc[i][j] = __builtin_amdgcn_mfma_f32_16x16x32_f16(av[i], blv[j], acc[i][j], 0, 0, 0);
                }
        }
        __syncthreads();  // all frag reads done before epilogue overwrites staging

        // epilogue: acc -> yb (t-major, stride 132)
#pragma unroll
        for (int i = 0; i < 4; ++i)
#pragma unroll
            for (int j = 0; j < 2; ++j) {
                int tr = wm * 64 + i * 16 + kq * 4;
                int hc = wn * 32 + j * 16 + fr;
#pragma unroll
                for (int r = 0; r < 4; ++r)
                    yb[(tr + r) * 132 + hc] = acc[i][j][r];
            }
        __syncthreads();

        // sequential scan (waves 0-1); 8-deep ring; spikes -> global directly
        if (tid < 128) {
            f16* sq = S1 + ((size_t)n * TT + t0) * HH + h0g + tid;
            float rb_[8];
#pragma unroll
            for (int j = 0; j < 8; ++j) rb_[j] = yb[j * 132 + tid];
            int t = 0;
            for (; t + 8 <= TCe; t += 8) {
#pragma unroll
                for (int j = 0; j < 8; ++j) {
                    float xv = rb_[j];
                    int tn = t + j + 8;
                    rb_[j] = (tn < TCe) ? yb[tn * 132 + tid] : 0.f;
                    a1 = D_SR * (a1 + p1);
                    p1 = D_SR * p1 + xv;
                    float ut = C_SR * a1;
                    a2 = D_RF * (a2 + p2);
                    float u = ut + C_RF * a2;
                    float s = (u >= THETA) ? 1.0f : 0.0f;
                    p2 = D_RF * p2 + REFS * s;
                    sq[(size_t)(t + j) * HH] = (f16)s;
                }
            }
            int rem = TCe - t;
#pragma unroll
            for (int j = 0; j < 8; ++j) {
                if (j < rem) {
                    float xv = rb_[j];
                    a1 = D_SR * (a1 + p1);
                    p1 = D_SR * p1 + xv;
                    float ut = C_SR * a1;
                    a2 = D_RF * (a2 + p2);
                    float u = ut + C_RF * a2;
                    float s = (u >= THETA) ? 1.0f : 0.0f;
                    p2 = D_RF * p2 + REFS * s;
                    sq[(size_t)(t + j) * HH] = (f16)s;
                }
            }
        }
        __syncthreads();  // yb reads done; next chunk's staging may overwrite
    }
}

// ---------------- GEMM2 (MFMA, split-f16, dbuf, 64-row tiles) ---------------
// grid 500 (2 blocks/CU); 256 thr; tile 64 m x 32 o; K=1024, BK=32.
__launch_bounds__(256)
__global__ void gemm2_mfma(const f16* __restrict__ S1, const f16* __restrict__ W2h,
                           const f16* __restrict__ W2l, float* __restrict__ Y2) {
    __shared__ __align__(16) f16 As[2][64 * 32];  // 2 x 4 KB
    __shared__ __align__(16) f16 Bh[2][32 * 32];  // 2 x 2 KB
    __shared__ __align__(16) f16 Bl[2][32 * 32];  // 2 x 2 KB

    const int tid = threadIdx.x;
    const int wave = tid >> 6, lane = tid & 63;
    const int m0 = blockIdx.x * 64;
    const int fr = lane & 15, kq = lane >> 4;

    const f16* gA = S1 + (size_t)(m0 + wave * 16 + (lane >> 2)) * HH + (lane & 3) * 8;
    const f16* gB = (wave < 2 ? W2h : W2l) + (size_t)((wave & 1) * 16 + (lane >> 2)) * HH + (lane & 3) * 8;

    auto stage = [&](int kk2, int b) {
        const int ko = kk2 * 32;
        gl2lds16(gA + ko, &As[b][wave * 512]);
        gl2lds16(gB + ko, (wave < 2 ? &Bh[b][0] : &Bl[b][0]) + (wave & 1) * 512);
    };

    stage(0, 0);

    f32x4 acc[2] = {};
    for (int kk = 0; kk < HH / 32; ++kk) {
        __syncthreads();
        if (kk < HH / 32 - 1) stage(kk + 1, (kk + 1) & 1);
        const int b = kk & 1;

        f16x8 a, bh[2], bl[2];
        a = *(const f16x8*)(&As[b][(wave * 16 + fr) * 32 + kq * 8]);
#pragma unroll
        for (int j = 0; j < 2; ++j) {
            bh[j] = *(const f16x8*)(&Bh[b][(j * 16 + fr) * 32 + kq * 8]);
            bl[j] = *(const f16x8*)(&Bl[b][(j * 16 + fr) * 32 + kq * 8]);
        }
#pragma unroll
        for (int j = 0; j < 2; ++j) {
            acc[j] = __builtin_amdgcn_mfma_f32_16x16x32_f16(a, bh[j], acc[j], 0, 0, 0);
            acc[j] = __builtin_amdgcn_mfma_f32_16x16x32_f16(a, bl[j], acc[j], 0, 0, 0);
        }
    }

#pragma unroll
    for (int j = 0; j < 2; ++j) {
        int rbase = m0 + wave * 16 + kq * 4;
        int cc = j * 16 + fr;
        float* p = Y2 + (size_t)rbase * 32 + cc;
#pragma unroll
        for (int r = 0; r < 4; ++r)
            p[(size_t)r * 32] = acc[j][r];
    }
}

// ---------------- scan2: single-phase LDS, static-index ring ----------------
__launch_bounds__(256)
__global__ void scan2_k(const float* __restrict__ Y2, float* __restrict__ Out) {
    __shared__ float yc[TT * 32];    // 64,000 B
    __shared__ float sb[OO * TT];    // 36,000 B
    const int n = blockIdx.x, tid = threadIdx.x;

    const float4* src = (const float4*)(Y2 + (size_t)n * TT * 32);
    float4* dst = (float4*)yc;
    for (int i = tid; i < TT * 8; i += 256) dst[i] = src[i];
    __syncthreads();

    if (tid < 32) {
        float p1 = 0.f, a1 = 0.f, p2 = 0.f, a2 = 0.f;
        float rb_[8];
#pragma unroll
        for (int j = 0; j < 8; ++j) rb_[j] = yc[j * 32 + tid];
        int t = 0;
        for (; t + 8 <= TT; t += 8) {
#pragma unroll
            for (int j = 0; j < 8; ++j) {
                float xv = rb_[j];
                int tn = t + j + 8;
                rb_[j] = (tn < TT) ? yc[tn * 32 + tid] : 0.f;
                a1 = D_SR * (a1 + p1);
                p1 = D_SR * p1 + xv;
                float ut = C_SR * a1;
                a2 = D_RF * (a2 + p2);
                float u = ut + C_RF * a2;
                float s = (u >= THETA) ? 1.0f : 0.0f;
                p2 = D_RF * p2 + REFS * s;
                if (tid < OO) sb[tid * TT + t + j] = s;
            }
        }
#pragma unroll
        for (int j = 0; j < 8; ++j) {
            if (t + j < TT) {
                float xv = rb_[j];
                a1 = D_SR * (a1 + p1);
                p1 = D_SR * p1 + xv;
                float ut = C_SR * a1;
                a2 = D_RF * (a2 + p2);
                float u = ut + C_RF * a2;
                float s = (u >= THETA) ? 1.0f : 0.0f;
                p2 = D_RF * p2 + REFS * s;
                if (tid < OO) sb[tid * TT + t + j] = s;
            }
        }
    }
    __syncthreads();

    float* on = Out + (size_t)n * OO * TT;
    for (int e = tid; e < OO * TT; e += 256) on[e] = sb[e];
}

extern "C" void kernel_launch(void* const* d_in, const int* in_sizes, int n_in,
                              void* d_out, int out_size, void* d_ws, size_t ws_size,
                              hipStream_t stream) {
    const float* X  = (const float*)d_in[0];
    const float* W1 = (const float*)d_in[1];
    const float* W2 = (const float*)d_in[2];
    float* out = (float*)d_out;

    const size_t s_s1 = (size_t)NN * TT * HH * 2;   // 65,536,000
    const size_t s_Xb = (size_t)NN * TT * II * 2;   // 16,384,000
    const size_t s_W  = (size_t)HH * II * 2;        //    524,288 (x2)
    const size_t s_W2 = (size_t)32 * HH * 2;        //     65,536 (x2)
    // + y2 4,096,000 => ~87 MB total

    char* w = (char*)d_ws;
    f16*   s1b = (f16*)w;  w += s_s1;
    f16*   Xb  = (f16*)w;  w += s_Xb;
    f16*   W1h = (f16*)w;  w += s_W;
    f16*   W1l = (f16*)w;  w += s_W;
    f16*   W2h = (f16*)w;  w += s_W2;
    f16*   W2l = (f16*)w;  w += s_W2;
    float* y2  = (float*)w;

    prep_all<<<3200, 256, 0, stream>>>(X, W1, W2, Xb, W1h, W1l, W2h, W2l);

    gemm1_scan1<<<dim3(8, NN), 512, 0, stream>>>(Xb, W1h, W1l, s1b);

    gemm2_mfma<<<(NN * TT) / 64, 256, 0, stream>>>(s1b, W2h, W2l, y2);
    scan2_k<<<NN, 256, 0, stream>>>(y2, out);
}